// Round 2
// baseline (1248.940 us; speedup 1.0000x reference)
//
#include <hip/hip_runtime.h>
#include <hip/hip_bf16.h>

// Problem constants
#define NB 4
#define NT 256
#define NU 128
#define DENC 512
#define DPRED 640
#define NH 640
#define NV 1025
#define NVP 1152      // V padded to 72 tiles of 16 -> uniform 9 tiles per wave (8 waves)
#define NTILES 72
#define JT 9          // tiles per wave (72 / 8 waves)
#define JWAVES 8

typedef __attribute__((ext_vector_type(8))) short short8;
typedef __attribute__((ext_vector_type(4))) float f32x4;

__device__ __forceinline__ unsigned short bfu(float a) {
    union { __hip_bfloat16 h; unsigned short u; } cv;
    cv.h = __float2bfloat16(a);
    return cv.u;
}

__device__ __forceinline__ unsigned pk2(float a, float b) {
    union { __hip_bfloat162 h; unsigned u; } cv;
    cv.h = __float22bfloat162_rn(float2{a, b});
    return cv.u;
}

__device__ __forceinline__ short8 pack_relu(f32x4 x, f32x4 y) {
    union { short8 s; unsigned u[4]; } r;
    r.u[0] = pk2(fmaxf(x[0], 0.f), fmaxf(x[1], 0.f));
    r.u[1] = pk2(fmaxf(x[2], 0.f), fmaxf(x[3], 0.f));
    r.u[2] = pk2(fmaxf(y[0], 0.f), fmaxf(y[1], 0.f));
    r.u[3] = pk2(fmaxf(y[2], 0.f), fmaxf(y[3], 0.f));
    return r.s;
}

// W_out fp32 [1025][640] -> bf16 [1152][640] zero-padded; bias -> [1152], pads = -1e30
__global__ __launch_bounds__(256) void prep_kernel(const float* __restrict__ Wo,
                                                   const float* __restrict__ bo,
                                                   unsigned short* __restrict__ Wb,
                                                   float* __restrict__ biasp) {
    int idx = blockIdx.x * 256 + threadIdx.x;
    if (idx < NVP * NH) {
        int v = idx / NH;
        Wb[idx] = (v < NV) ? bfu(Wo[idx]) : (unsigned short)0;
    }
    if (idx < NVP) biasp[idx] = (idx < NV) ? bo[idx] : -1e30f;
}

// Projection GEMM: out[b*L + l][n] = sum_k X[b][k][l] * W[n][k] + bias[n]
// X: [NB][K][L] fp32 (strided input), W: [640][K], out: [NB*L][640] fp32
// Block: 256 thr, tile M=32 x N=64, K-step 32. bf16 MFMA 16x16x32.
__global__ __launch_bounds__(256) void proj_kernel(const float* __restrict__ X,
                                                   const float* __restrict__ W,
                                                   const float* __restrict__ bias,
                                                   float* __restrict__ out,
                                                   int L, int K) {
    __shared__ unsigned short As[32][40];   // [m][k], +8 pad keeps 16B align, breaks stride
    __shared__ unsigned short Bs[64][40];   // [n][k]
    int tid = threadIdx.x;
    int wave = tid >> 6, lane = tid & 63;
    int col16 = lane & 15, kgrp = lane >> 4;
    int m0 = blockIdx.x * 32;
    int n0 = blockIdx.y * 64;
    int b = m0 / L, l0 = m0 % L;
    const float* Xb = X + (size_t)b * K * L;

    float bv = bias[n0 + wave * 16 + col16];
    f32x4 c0 = {bv, bv, bv, bv};
    f32x4 c1 = c0;

    int ac = tid >> 3;          // k-local 0..31
    int ar = (tid & 7) * 4;     // m-local 0,4,..28
    int bn = tid >> 2;          // n-local 0..63
    int bc = (tid & 3) * 8;     // k-local 0,8,16,24

    for (int k0 = 0; k0 < K; k0 += 32) {
        f32x4 av  = *(const f32x4*)(Xb + (size_t)(k0 + ac) * L + l0 + ar);
        f32x4 bw0 = *(const f32x4*)(W + (size_t)(n0 + bn) * K + k0 + bc);
        f32x4 bw1 = *(const f32x4*)(W + (size_t)(n0 + bn) * K + k0 + bc + 4);
        __syncthreads();   // previous iter's frag reads done before overwrite
        As[ar + 0][ac] = bfu(av[0]);
        As[ar + 1][ac] = bfu(av[1]);
        As[ar + 2][ac] = bfu(av[2]);
        As[ar + 3][ac] = bfu(av[3]);
        unsigned* bsrow = (unsigned*)&Bs[bn][bc];
        bsrow[0] = pk2(bw0[0], bw0[1]);
        bsrow[1] = pk2(bw0[2], bw0[3]);
        bsrow[2] = pk2(bw1[0], bw1[1]);
        bsrow[3] = pk2(bw1[2], bw1[3]);
        __syncthreads();
        short8 a0  = *(const short8*)&As[col16][kgrp * 8];
        short8 a1  = *(const short8*)&As[16 + col16][kgrp * 8];
        short8 bfr = *(const short8*)&Bs[wave * 16 + col16][kgrp * 8];
        c0 = __builtin_amdgcn_mfma_f32_16x16x32_bf16(a0, bfr, c0, 0, 0, 0);
        c1 = __builtin_amdgcn_mfma_f32_16x16x32_bf16(a1, bfr, c1, 0, 0, 0);
    }
    int n = n0 + wave * 16 + col16;
    #pragma unroll
    for (int i = 0; i < 4; ++i) {
        int r0 = kgrp * 4 + i;
        out[(size_t)(m0 + r0) * NH + n]      = c0[i];
        out[(size_t)(m0 + 16 + r0) * NH + n] = c1[i];
    }
}

// Joint kernel v3: one block per (bt, 64-u strip). 8 waves x 9 n-tiles (uniform,
// branch-free). Per-wave regs ~250 -> __launch_bounds__(512,2) = 2 waves/SIMD
// (v2 was 1 wave/SIMD at 272 accs; latency-bound). Depth-1 register prefetch of
// both W fragments and g rows.
__global__ __launch_bounds__(512, 2) void joint_kernel(const float* __restrict__ f,
                                                       const float* __restrict__ g,
                                                       const unsigned short* __restrict__ Wb,
                                                       const float* __restrict__ biasp,
                                                       float* __restrict__ out) {
    __shared__ float fs[NH];
    __shared__ float redm[JWAVES][64];
    __shared__ float reds[JWAVES][64];
    int tid = threadIdx.x;
    int wave = tid >> 6, lane = tid & 63;
    int col16 = lane & 15, kgrp = lane >> 4;
    int bt = blockIdx.x >> 1;          // b*NT + t
    int u0 = (blockIdx.x & 1) * 64;
    int b = bt >> 8;                   // NT = 256

    for (int i = tid; i < NH; i += 512) fs[i] = f[(size_t)bt * NH + i];
    __syncthreads();

    int tstart = wave * JT;
    const unsigned short* wbp = Wb + (size_t)(tstart * 16 + col16) * NH + kgrp * 8;
    const float* gp[4];
    #pragma unroll
    for (int m = 0; m < 4; ++m)
        gp[m] = g + (size_t)(b * NU + u0 + m * 16 + col16) * NH + kgrp * 8;

    f32x4 c[JT][4];
    #pragma unroll
    for (int j = 0; j < JT; ++j) {
        float bv = biasp[(tstart + j) * 16 + col16];
        f32x4 cv = {bv, bv, bv, bv};
        c[j][0] = cv; c[j][1] = cv; c[j][2] = cv; c[j][3] = cv;
    }

    // prologue: W fragments and g rows for k-step 0
    short8 bf[JT];
    #pragma unroll
    for (int j = 0; j < JT; ++j)
        bf[j] = *(const short8*)(wbp + (size_t)j * 16 * NH);
    f32x4 gpre[4][2];
    #pragma unroll
    for (int m = 0; m < 4; ++m) {
        gpre[m][0] = *(const f32x4*)(gp[m]);
        gpre[m][1] = *(const f32x4*)(gp[m] + 4);
    }

    // main loop, k-steps 0..18 with depth-1 register prefetch of k-step ks+1
    for (int ks = 0; ks < 19; ++ks) {
        int kb = ks * 32 + kgrp * 8;
        f32x4 fa0 = *(const f32x4*)(fs + kb);
        f32x4 fa1 = *(const f32x4*)(fs + kb + 4);
        short8 a[4];
        #pragma unroll
        for (int m = 0; m < 4; ++m) {
            a[m] = pack_relu(fa0 + gpre[m][0], fa1 + gpre[m][1]);
            gpre[m][0] = *(const f32x4*)(gp[m] + (ks + 1) * 32);      // prefetch ks+1
            gpre[m][1] = *(const f32x4*)(gp[m] + (ks + 1) * 32 + 4);
        }
        const unsigned short* wk = wbp + (ks + 1) * 32;
        #pragma unroll
        for (int j = 0; j < JT; ++j) {
            short8 bj = bf[j];
            bf[j] = *(const short8*)(wk + (size_t)j * 16 * NH);       // prefetch ks+1
            c[j][0] = __builtin_amdgcn_mfma_f32_16x16x32_bf16(a[0], bj, c[j][0], 0, 0, 0);
            c[j][1] = __builtin_amdgcn_mfma_f32_16x16x32_bf16(a[1], bj, c[j][1], 0, 0, 0);
            c[j][2] = __builtin_amdgcn_mfma_f32_16x16x32_bf16(a[2], bj, c[j][2], 0, 0, 0);
            c[j][3] = __builtin_amdgcn_mfma_f32_16x16x32_bf16(a[3], bj, c[j][3], 0, 0, 0);
        }
    }
    {   // final k-step ks = 19, no prefetch
        int kb = 19 * 32 + kgrp * 8;
        f32x4 fa0 = *(const f32x4*)(fs + kb);
        f32x4 fa1 = *(const f32x4*)(fs + kb + 4);
        short8 a[4];
        #pragma unroll
        for (int m = 0; m < 4; ++m)
            a[m] = pack_relu(fa0 + gpre[m][0], fa1 + gpre[m][1]);
        #pragma unroll
        for (int j = 0; j < JT; ++j) {
            c[j][0] = __builtin_amdgcn_mfma_f32_16x16x32_bf16(a[0], bf[j], c[j][0], 0, 0, 0);
            c[j][1] = __builtin_amdgcn_mfma_f32_16x16x32_bf16(a[1], bf[j], c[j][1], 0, 0, 0);
            c[j][2] = __builtin_amdgcn_mfma_f32_16x16x32_bf16(a[2], bf[j], c[j][2], 0, 0, 0);
            c[j][3] = __builtin_amdgcn_mfma_f32_16x16x32_bf16(a[3], bf[j], c[j][3], 0, 0, 0);
        }
    }

    // ---- fused log-softmax epilogue ----
    // C layout: col = n_tile*16 + (lane&15); row = m*16 + (lane>>4)*4 + reg  (m89-verified)
    float mx[4][4], sl[4][4];
    #pragma unroll
    for (int m = 0; m < 4; ++m) {
        #pragma unroll
        for (int i = 0; i < 4; ++i) {
            float v = -3e38f;
            #pragma unroll
            for (int j = 0; j < JT; ++j) v = fmaxf(v, c[j][m][i]);
            #pragma unroll
            for (int d = 1; d < 16; d <<= 1)
                v = fmaxf(v, __shfl_xor(v, d, 64));
            mx[m][i] = v;
        }
    }
    if (col16 == 0) {
        #pragma unroll
        for (int m = 0; m < 4; ++m)
            #pragma unroll
            for (int i = 0; i < 4; ++i)
                redm[wave][m * 16 + kgrp * 4 + i] = mx[m][i];
    }
    __syncthreads();
    #pragma unroll
    for (int m = 0; m < 4; ++m)
        #pragma unroll
        for (int i = 0; i < 4; ++i) {
            int r = m * 16 + kgrp * 4 + i;
            float v = redm[0][r];
            #pragma unroll
            for (int w = 1; w < JWAVES; ++w) v = fmaxf(v, redm[w][r]);
            mx[m][i] = v;
        }
    #pragma unroll
    for (int m = 0; m < 4; ++m) {
        #pragma unroll
        for (int i = 0; i < 4; ++i) {
            float ssum = 0.f;
            #pragma unroll
            for (int j = 0; j < JT; ++j) ssum += __expf(c[j][m][i] - mx[m][i]);
            #pragma unroll
            for (int d = 1; d < 16; d <<= 1)
                ssum += __shfl_xor(ssum, d, 64);
            sl[m][i] = ssum;
        }
    }
    if (col16 == 0) {
        #pragma unroll
        for (int m = 0; m < 4; ++m)
            #pragma unroll
            for (int i = 0; i < 4; ++i)
                reds[wave][m * 16 + kgrp * 4 + i] = sl[m][i];
    }
    __syncthreads();
    #pragma unroll
    for (int m = 0; m < 4; ++m)
        #pragma unroll
        for (int i = 0; i < 4; ++i) {
            int r = m * 16 + kgrp * 4 + i;
            float S = 0.f;
            #pragma unroll
            for (int w = 0; w < JWAVES; ++w) S += reds[w][r];
            sl[m][i] = mx[m][i] + __logf(S);   // m + log(sum exp(x-m))
        }

    size_t orow0 = (size_t)bt * NU + u0;
    #pragma unroll
    for (int m = 0; m < 4; ++m) {
        #pragma unroll
        for (int j = 0; j < JT; ++j) {
            int col = (tstart + j) * 16 + col16;
            if (col < NV) {
                #pragma unroll
                for (int i = 0; i < 4; ++i) {
                    size_t row = orow0 + m * 16 + kgrp * 4 + i;
                    out[row * (size_t)NV + col] = c[j][m][i] - sl[m][i];
                }
            }
        }
    }
}

extern "C" void kernel_launch(void* const* d_in, const int* in_sizes, int n_in,
                              void* d_out, int out_size, void* d_ws, size_t ws_size,
                              hipStream_t stream) {
    const float* enc    = (const float*)d_in[0];  // [4][512][256]
    const float* dec    = (const float*)d_in[1];  // [4][640][128]
    const float* W_enc  = (const float*)d_in[2];  // [640][512]
    const float* b_enc  = (const float*)d_in[3];  // [640]
    const float* W_pred = (const float*)d_in[4];  // [640][640]
    const float* b_pred = (const float*)d_in[5];  // [640]
    const float* W_out  = (const float*)d_in[6];  // [1025][640]
    const float* b_out  = (const float*)d_in[7];  // [1025]
    float* out = (float*)d_out;

    char* ws = (char*)d_ws;
    unsigned short* Wb = (unsigned short*)ws;          // 1,474,560 B (bf16 [1152][640])
    float* biasp = (float*)(ws + 1474560);             // 4,608 B
    float* fbuf  = (float*)(ws + 1479168);             // 2,621,440 B ([1024][640] fp32)
    float* gbuf  = (float*)(ws + 4100608);             // 1,310,720 B ([512][640] fp32)

    prep_kernel<<<(NVP * NH + 255) / 256, 256, 0, stream>>>(W_out, b_out, Wb, biasp);
    proj_kernel<<<dim3((NB * NT) / 32, NH / 64), 256, 0, stream>>>(enc, W_enc, b_enc, fbuf, NT, DENC);
    proj_kernel<<<dim3((NB * NU) / 32, NH / 64), 256, 0, stream>>>(dec, W_pred, b_pred, gbuf, NU, DPRED);
    joint_kernel<<<NB * NT * (NU / 64), 512, 0, stream>>>(fbuf, gbuf, Wb, biasp, out);
}

// Round 3
// 1180.422 us; speedup vs baseline: 1.0580x; 1.0580x over previous
//
#include <hip/hip_runtime.h>
#include <hip/hip_bf16.h>

// Problem constants
#define NB 4
#define NT 256
#define NU 128
#define DENC 512
#define DPRED 640
#define NH 640
#define NV 1025
#define NVP 1152      // V padded to 72 tiles of 16 -> uniform 9 tiles per wave (8 waves)
#define NTILES 72
#define JT 9          // tiles per wave (72 / 8 waves)
#define JWAVES 8
#define KSTEPS 20     // 640 / 32
#define WSLAB (NVP * 32)   // 36864 bf16 elems per k-slab

typedef __attribute__((ext_vector_type(8))) short short8;
typedef __attribute__((ext_vector_type(4))) float f32x4;

__device__ __forceinline__ unsigned short bfu(float a) {
    union { __hip_bfloat16 h; unsigned short u; } cv;
    cv.h = __float2bfloat16(a);
    return cv.u;
}

__device__ __forceinline__ unsigned pk2(float a, float b) {
    union { __hip_bfloat162 h; unsigned u; } cv;
    cv.h = __float22bfloat162_rn(float2{a, b});
    return cv.u;
}

__device__ __forceinline__ short8 pack_relu(f32x4 x, f32x4 y) {
    union { short8 s; unsigned u[4]; } r;
    r.u[0] = pk2(fmaxf(x[0], 0.f), fmaxf(x[1], 0.f));
    r.u[1] = pk2(fmaxf(x[2], 0.f), fmaxf(x[3], 0.f));
    r.u[2] = pk2(fmaxf(y[0], 0.f), fmaxf(y[1], 0.f));
    r.u[3] = pk2(fmaxf(y[2], 0.f), fmaxf(y[3], 0.f));
    return r.s;
}

// async global -> LDS, 16 B per lane; LDS dest = wave-uniform base + lane*16
__device__ __forceinline__ void gload_lds16(const void* g, void* l) {
    __builtin_amdgcn_global_load_lds(
        (const __attribute__((address_space(1))) unsigned int*)g,
        (__attribute__((address_space(3))) unsigned int*)l, 16, 0, 0);
}

// prep v2: W_out fp32 [1025][640] -> WbT bf16 [20][1152][32] (k-slab-major),
// with LDS bank-swizzle baked in: slab content at (r, slot s) holds source slot
// s ^ f(r), f(r) = ((r>>2)^r)&3. Consumer reads slot kgrp^f(r) -> original data.
// bias -> [1152], pads = -1e30. Grid: dim3(144, 20).
__global__ __launch_bounds__(256) void prep_kernel(const float* __restrict__ Wo,
                                                   const float* __restrict__ bo,
                                                   unsigned short* __restrict__ WbT,
                                                   float* __restrict__ biasp) {
    int idx = blockIdx.x * 256 + threadIdx.x;     // 0 .. 36863 within slab
    int ks = blockIdx.y;
    int r = idx >> 5;         // row 0..1151
    int kk = idx & 31;        // 0..31 within slab row
    int s = kk >> 3, e = kk & 7;
    int f = ((r >> 2) ^ r) & 3;
    int scol = ks * 32 + (((s ^ f) & 3) << 3) + e;
    WbT[(size_t)ks * WSLAB + idx] = (r < NV) ? bfu(Wo[r * NH + scol]) : (unsigned short)0;
    if (ks == 0 && idx < NVP) biasp[idx] = (idx < NV) ? bo[idx] : -1e30f;
}

// Projection GEMM: out[b*L + l][n] = sum_k X[b][k][l] * W[n][k] + bias[n]
__global__ __launch_bounds__(256) void proj_kernel(const float* __restrict__ X,
                                                   const float* __restrict__ W,
                                                   const float* __restrict__ bias,
                                                   float* __restrict__ out,
                                                   int L, int K) {
    __shared__ unsigned short As[32][40];
    __shared__ unsigned short Bs[64][40];
    int tid = threadIdx.x;
    int wave = tid >> 6, lane = tid & 63;
    int col16 = lane & 15, kgrp = lane >> 4;
    int m0 = blockIdx.x * 32;
    int n0 = blockIdx.y * 64;
    int b = m0 / L, l0 = m0 % L;
    const float* Xb = X + (size_t)b * K * L;

    float bv = bias[n0 + wave * 16 + col16];
    f32x4 c0 = {bv, bv, bv, bv};
    f32x4 c1 = c0;

    int ac = tid >> 3;
    int ar = (tid & 7) * 4;
    int bn = tid >> 2;
    int bc = (tid & 3) * 8;

    for (int k0 = 0; k0 < K; k0 += 32) {
        f32x4 av  = *(const f32x4*)(Xb + (size_t)(k0 + ac) * L + l0 + ar);
        f32x4 bw0 = *(const f32x4*)(W + (size_t)(n0 + bn) * K + k0 + bc);
        f32x4 bw1 = *(const f32x4*)(W + (size_t)(n0 + bn) * K + k0 + bc + 4);
        __syncthreads();
        As[ar + 0][ac] = bfu(av[0]);
        As[ar + 1][ac] = bfu(av[1]);
        As[ar + 2][ac] = bfu(av[2]);
        As[ar + 3][ac] = bfu(av[3]);
        unsigned* bsrow = (unsigned*)&Bs[bn][bc];
        bsrow[0] = pk2(bw0[0], bw0[1]);
        bsrow[1] = pk2(bw0[2], bw0[3]);
        bsrow[2] = pk2(bw1[0], bw1[1]);
        bsrow[3] = pk2(bw1[2], bw1[3]);
        __syncthreads();
        short8 a0  = *(const short8*)&As[col16][kgrp * 8];
        short8 a1  = *(const short8*)&As[16 + col16][kgrp * 8];
        short8 bfr = *(const short8*)&Bs[wave * 16 + col16][kgrp * 8];
        c0 = __builtin_amdgcn_mfma_f32_16x16x32_bf16(a0, bfr, c0, 0, 0, 0);
        c1 = __builtin_amdgcn_mfma_f32_16x16x32_bf16(a1, bfr, c1, 0, 0, 0);
    }
    int n = n0 + wave * 16 + col16;
    #pragma unroll
    for (int i = 0; i < 4; ++i) {
        int r0 = kgrp * 4 + i;
        out[(size_t)(m0 + r0) * NH + n]      = c0[i];
        out[(size_t)(m0 + 16 + r0) * NH + n] = c1[i];
    }
}

// Joint kernel v4: 512 thr, 8 waves x 9 n-tiles, M=64 u-rows. W staged in LDS
// (double-buffered k-slabs, global_load_lds w=16, swizzle pre-baked by prep).
// No per-wave W registers -> live set ~144 AGPR acc + ~90 VGPR -> fits (512,2)
// = 2 waves/SIMD without spilling (R2 spilled at same occupancy: FETCH +22GB).
__global__ __launch_bounds__(512, 2) void joint_kernel(const float* __restrict__ f,
                                                       const float* __restrict__ g,
                                                       const unsigned short* __restrict__ WbT,
                                                       const float* __restrict__ biasp,
                                                       float* __restrict__ out) {
    __shared__ unsigned short Ws[2][WSLAB];   // 2 x 73728 B
    __shared__ float fs[NH];
    __shared__ float redm[JWAVES][64];
    __shared__ float reds[JWAVES][64];
    int tid = threadIdx.x;
    int wave = tid >> 6, lane = tid & 63;
    int col16 = lane & 15, kgrp = lane >> 4;
    int bt = blockIdx.x >> 1;          // b*NT + t
    int u0 = (blockIdx.x & 1) * 64;
    int b = bt >> 8;                   // NT = 256

    for (int i = tid; i < NH; i += 512) fs[i] = f[(size_t)bt * NH + i];

    int tstart = wave * JT;
    const float* gp[4];
    #pragma unroll
    for (int m = 0; m < 4; ++m)
        gp[m] = g + (size_t)(b * NU + u0 + m * 16 + col16) * NH + kgrp * 8;

    f32x4 c[JT][4];
    #pragma unroll
    for (int j = 0; j < JT; ++j) {
        float bv = biasp[(tstart + j) * 16 + col16];
        f32x4 cv = {bv, bv, bv, bv};
        c[j][0] = cv; c[j][1] = cv; c[j][2] = cv; c[j][3] = cv;
    }

    // prologue: stage k-slab 0 into buf 0 (this wave stages its own 9 tiles)
    #pragma unroll
    for (int j = 0; j < JT; ++j)
        gload_lds16(WbT + (size_t)(tstart + j) * 512 + lane * 8,
                    &Ws[0][(tstart + j) * 512]);

    // g prefetch for k-step 0
    f32x4 gpre[4][2];
    #pragma unroll
    for (int m = 0; m < 4; ++m) {
        gpre[m][0] = *(const f32x4*)(gp[m]);
        gpre[m][1] = *(const f32x4*)(gp[m] + 4);
    }

    // consumer-side swizzled slot (lane-invariant across tiles/k-steps)
    int slx = ((kgrp ^ ((col16 >> 2) ^ col16)) & 3) * 8;
    int rdoff = tstart * 512 + col16 * 32 + slx;

    __syncthreads();   // fs + slab0 staged (barrier drains vmcnt)

    int buf = 0;
    for (int ks = 0; ks < KSTEPS; ++ks) {
        if (ks < KSTEPS - 1) {
            const unsigned short* wn = WbT + (size_t)(ks + 1) * WSLAB;
            #pragma unroll
            for (int j = 0; j < JT; ++j)
                gload_lds16(wn + (size_t)(tstart + j) * 512 + lane * 8,
                            &Ws[buf ^ 1][(tstart + j) * 512]);
        }
        int kb = ks * 32 + kgrp * 8;
        f32x4 fa0 = *(const f32x4*)(fs + kb);
        f32x4 fa1 = *(const f32x4*)(fs + kb + 4);
        short8 a[4];
        #pragma unroll
        for (int m = 0; m < 4; ++m) {
            a[m] = pack_relu(fa0 + gpre[m][0], fa1 + gpre[m][1]);
            if (ks < KSTEPS - 1) {
                gpre[m][0] = *(const f32x4*)(gp[m] + (ks + 1) * 32);
                gpre[m][1] = *(const f32x4*)(gp[m] + (ks + 1) * 32 + 4);
            }
        }
        const unsigned short* wb = &Ws[buf][rdoff];
        #pragma unroll
        for (int j = 0; j < JT; ++j) {
            short8 bj = *(const short8*)(wb + j * 512);
            c[j][0] = __builtin_amdgcn_mfma_f32_16x16x32_bf16(a[0], bj, c[j][0], 0, 0, 0);
            c[j][1] = __builtin_amdgcn_mfma_f32_16x16x32_bf16(a[1], bj, c[j][1], 0, 0, 0);
            c[j][2] = __builtin_amdgcn_mfma_f32_16x16x32_bf16(a[2], bj, c[j][2], 0, 0, 0);
            c[j][3] = __builtin_amdgcn_mfma_f32_16x16x32_bf16(a[3], bj, c[j][3], 0, 0, 0);
        }
        __syncthreads();   // drains staging vmcnt; all reads of buf done
        buf ^= 1;
    }

    // ---- fused log-softmax epilogue ----
    // C layout: col = n_tile*16 + (lane&15); row = m*16 + (lane>>4)*4 + reg
    float mx[4][4], sl[4][4];
    #pragma unroll
    for (int m = 0; m < 4; ++m) {
        #pragma unroll
        for (int i = 0; i < 4; ++i) {
            float v = -3e38f;
            #pragma unroll
            for (int j = 0; j < JT; ++j) v = fmaxf(v, c[j][m][i]);
            #pragma unroll
            for (int d = 1; d < 16; d <<= 1)
                v = fmaxf(v, __shfl_xor(v, d, 64));
            mx[m][i] = v;
        }
    }
    if (col16 == 0) {
        #pragma unroll
        for (int m = 0; m < 4; ++m)
            #pragma unroll
            for (int i = 0; i < 4; ++i)
                redm[wave][m * 16 + kgrp * 4 + i] = mx[m][i];
    }
    __syncthreads();
    #pragma unroll
    for (int m = 0; m < 4; ++m)
        #pragma unroll
        for (int i = 0; i < 4; ++i) {
            int r = m * 16 + kgrp * 4 + i;
            float v = redm[0][r];
            #pragma unroll
            for (int w = 1; w < JWAVES; ++w) v = fmaxf(v, redm[w][r]);
            mx[m][i] = v;
        }
    #pragma unroll
    for (int m = 0; m < 4; ++m) {
        #pragma unroll
        for (int i = 0; i < 4; ++i) {
            float ssum = 0.f;
            #pragma unroll
            for (int j = 0; j < JT; ++j) ssum += __expf(c[j][m][i] - mx[m][i]);
            #pragma unroll
            for (int d = 1; d < 16; d <<= 1)
                ssum += __shfl_xor(ssum, d, 64);
            sl[m][i] = ssum;
        }
    }
    if (col16 == 0) {
        #pragma unroll
        for (int m = 0; m < 4; ++m)
            #pragma unroll
            for (int i = 0; i < 4; ++i)
                reds[wave][m * 16 + kgrp * 4 + i] = sl[m][i];
    }
    __syncthreads();
    #pragma unroll
    for (int m = 0; m < 4; ++m)
        #pragma unroll
        for (int i = 0; i < 4; ++i) {
            int r = m * 16 + kgrp * 4 + i;
            float S = 0.f;
            #pragma unroll
            for (int w = 0; w < JWAVES; ++w) S += reds[w][r];
            sl[m][i] = mx[m][i] + __logf(S);
        }

    size_t orow0 = (size_t)bt * NU + u0;
    #pragma unroll
    for (int m = 0; m < 4; ++m) {
        #pragma unroll
        for (int j = 0; j < JT; ++j) {
            int col = (tstart + j) * 16 + col16;
            if (col < NV) {
                #pragma unroll
                for (int i = 0; i < 4; ++i) {
                    size_t row = orow0 + m * 16 + kgrp * 4 + i;
                    out[row * (size_t)NV + col] = c[j][m][i] - sl[m][i];
                }
            }
        }
    }
}

extern "C" void kernel_launch(void* const* d_in, const int* in_sizes, int n_in,
                              void* d_out, int out_size, void* d_ws, size_t ws_size,
                              hipStream_t stream) {
    const float* enc    = (const float*)d_in[0];  // [4][512][256]
    const float* dec    = (const float*)d_in[1];  // [4][640][128]
    const float* W_enc  = (const float*)d_in[2];  // [640][512]
    const float* b_enc  = (const float*)d_in[3];  // [640]
    const float* W_pred = (const float*)d_in[4];  // [640][640]
    const float* b_pred = (const float*)d_in[5];  // [640]
    const float* W_out  = (const float*)d_in[6];  // [1025][640]
    const float* b_out  = (const float*)d_in[7];  // [1025]
    float* out = (float*)d_out;

    char* ws = (char*)d_ws;
    unsigned short* WbT = (unsigned short*)ws;         // 1,474,560 B (bf16 [20][1152][32])
    float* biasp = (float*)(ws + 1474560);             // 4,608 B
    float* fbuf  = (float*)(ws + 1479168);             // 2,621,440 B ([1024][640] fp32)
    float* gbuf  = (float*)(ws + 4100608);             // 1,310,720 B ([512][640] fp32)

    prep_kernel<<<dim3(WSLAB / 256, KSTEPS), 256, 0, stream>>>(W_out, b_out, WbT, biasp);
    proj_kernel<<<dim3((NB * NT) / 32, NH / 64), 256, 0, stream>>>(enc, W_enc, b_enc, fbuf, NT, DENC);
    proj_kernel<<<dim3((NB * NU) / 32, NH / 64), 256, 0, stream>>>(dec, W_pred, b_pred, gbuf, NU, DPRED);
    joint_kernel<<<NB * NT * (NU / 64), 512, 0, stream>>>(fbuf, gbuf, WbT, biasp, out);
}

// Round 4
// 1003.014 us; speedup vs baseline: 1.2452x; 1.1769x over previous
//
#include <hip/hip_runtime.h>
#include <hip/hip_bf16.h>

// Problem constants
#define NB 4
#define NT 256
#define NU 128
#define DENC 512
#define DPRED 640
#define NH 640
#define NV 1025
#define NVP 1152      // V padded to 72 tiles of 16 -> 18 tiles per wave (4 waves)
#define NTILES 72
#define JT 18         // tiles per wave (72 / 4 waves), 9 per half-slab
#define KSTEPS 20     // 640 / 32
#define WSLAB (NVP * 32)   // 36864 bf16 elems per k-slab (73728 B)

typedef __attribute__((ext_vector_type(8))) short short8;
typedef __attribute__((ext_vector_type(4))) float f32x4;

__device__ __forceinline__ unsigned short bfu(float a) {
    union { __hip_bfloat16 h; unsigned short u; } cv;
    cv.h = __float2bfloat16(a);
    return cv.u;
}

__device__ __forceinline__ unsigned pk2(float a, float b) {
    union { __hip_bfloat162 h; unsigned u; } cv;
    cv.h = __float22bfloat162_rn(float2{a, b});
    return cv.u;
}

__device__ __forceinline__ short8 pack_relu(f32x4 x, f32x4 y) {
    union { short8 s; unsigned u[4]; } r;
    r.u[0] = pk2(fmaxf(x[0], 0.f), fmaxf(x[1], 0.f));
    r.u[1] = pk2(fmaxf(x[2], 0.f), fmaxf(x[3], 0.f));
    r.u[2] = pk2(fmaxf(y[0], 0.f), fmaxf(y[1], 0.f));
    r.u[3] = pk2(fmaxf(y[2], 0.f), fmaxf(y[3], 0.f));
    return r.s;
}

// async global -> LDS, 16 B per lane; LDS dest = wave-uniform base + lane*16
__device__ __forceinline__ void gload_lds16(const void* g, void* l) {
    __builtin_amdgcn_global_load_lds(
        (const __attribute__((address_space(1))) unsigned int*)g,
        (__attribute__((address_space(3))) unsigned int*)l, 16, 0, 0);
}

// prep: W_out fp32 [1025][640] -> WbT bf16 [20][1152][32] (k-slab-major),
// LDS bank-swizzle pre-baked: (r, slot s) holds source slot s ^ f(r),
// f(r) = ((r>>2)^r)&3. Consumer reads slot kgrp^f(row) -> original data.
// bias -> [1152], pads = -1e30. Grid: dim3(144, 20).
__global__ __launch_bounds__(256) void prep_kernel(const float* __restrict__ Wo,
                                                   const float* __restrict__ bo,
                                                   unsigned short* __restrict__ WbT,
                                                   float* __restrict__ biasp) {
    int idx = blockIdx.x * 256 + threadIdx.x;     // 0 .. 36863 within slab
    int ks = blockIdx.y;
    int r = idx >> 5;         // row 0..1151
    int kk = idx & 31;        // 0..31 within slab row
    int s = kk >> 3, e = kk & 7;
    int f = ((r >> 2) ^ r) & 3;
    int scol = ks * 32 + (((s ^ f) & 3) << 3) + e;
    WbT[(size_t)ks * WSLAB + idx] = (r < NV) ? bfu(Wo[r * NH + scol]) : (unsigned short)0;
    if (ks == 0 && idx < NVP) biasp[idx] = (idx < NV) ? bo[idx] : -1e30f;
}

// Projection GEMM: out[b*L + l][n] = sum_k X[b][k][l] * W[n][k] + bias[n]
__global__ __launch_bounds__(256) void proj_kernel(const float* __restrict__ X,
                                                   const float* __restrict__ W,
                                                   const float* __restrict__ bias,
                                                   float* __restrict__ out,
                                                   int L, int K) {
    __shared__ unsigned short As[32][40];
    __shared__ unsigned short Bs[64][40];
    int tid = threadIdx.x;
    int wave = tid >> 6, lane = tid & 63;
    int col16 = lane & 15, kgrp = lane >> 4;
    int m0 = blockIdx.x * 32;
    int n0 = blockIdx.y * 64;
    int b = m0 / L, l0 = m0 % L;
    const float* Xb = X + (size_t)b * K * L;

    float bv = bias[n0 + wave * 16 + col16];
    f32x4 c0 = {bv, bv, bv, bv};
    f32x4 c1 = c0;

    int ac = tid >> 3;
    int ar = (tid & 7) * 4;
    int bn = tid >> 2;
    int bc = (tid & 3) * 8;

    for (int k0 = 0; k0 < K; k0 += 32) {
        f32x4 av  = *(const f32x4*)(Xb + (size_t)(k0 + ac) * L + l0 + ar);
        f32x4 bw0 = *(const f32x4*)(W + (size_t)(n0 + bn) * K + k0 + bc);
        f32x4 bw1 = *(const f32x4*)(W + (size_t)(n0 + bn) * K + k0 + bc + 4);
        __syncthreads();
        As[ar + 0][ac] = bfu(av[0]);
        As[ar + 1][ac] = bfu(av[1]);
        As[ar + 2][ac] = bfu(av[2]);
        As[ar + 3][ac] = bfu(av[3]);
        unsigned* bsrow = (unsigned*)&Bs[bn][bc];
        bsrow[0] = pk2(bw0[0], bw0[1]);
        bsrow[1] = pk2(bw0[2], bw0[3]);
        bsrow[2] = pk2(bw1[0], bw1[1]);
        bsrow[3] = pk2(bw1[2], bw1[3]);
        __syncthreads();
        short8 a0  = *(const short8*)&As[col16][kgrp * 8];
        short8 a1  = *(const short8*)&As[16 + col16][kgrp * 8];
        short8 bfr = *(const short8*)&Bs[wave * 16 + col16][kgrp * 8];
        c0 = __builtin_amdgcn_mfma_f32_16x16x32_bf16(a0, bfr, c0, 0, 0, 0);
        c1 = __builtin_amdgcn_mfma_f32_16x16x32_bf16(a1, bfr, c1, 0, 0, 0);
    }
    int n = n0 + wave * 16 + col16;
    #pragma unroll
    for (int i = 0; i < 4; ++i) {
        int r0 = kgrp * 4 + i;
        out[(size_t)(m0 + r0) * NH + n]      = c0[i];
        out[(size_t)(m0 + 16 + r0) * NH + n] = c1[i];
    }
}

// Joint kernel v5: M=32 u-rows, 256 thr, 4 waves x 18 tiles. W via LDS slab,
// split into two 36-tile halves double-buffered IN PLACE: stage half-X of
// k+1 during compute of half-Y of k. Regs ~220/thread -> (256,2) no-spill,
// 2 blocks/CU (LDS 77KB) -> cross-block latency hiding. setprio on MFMA (T5).
__global__ __launch_bounds__(256, 2) void joint_kernel(const float* __restrict__ f,
                                                       const float* __restrict__ g,
                                                       const unsigned short* __restrict__ WbT,
                                                       const float* __restrict__ biasp,
                                                       float* __restrict__ out) {
    __shared__ unsigned short Ws[WSLAB];   // 73728 B, tiles 0..71 (A:0-35, B:36-71)
    __shared__ float fs[NH];
    __shared__ float redm[4][32];
    __shared__ float reds[4][32];
    int tid = threadIdx.x;
    int wave = tid >> 6, lane = tid & 63;
    int col16 = lane & 15, kgrp = lane >> 4;
    int bt = blockIdx.x >> 2;          // b*NT + t
    int u0 = (blockIdx.x & 3) * 32;
    int b = bt >> 8;                   // NT = 256

    for (int i = tid; i < NH; i += 256) fs[i] = f[(size_t)bt * NH + i];

    int tA = wave * 9;        // this wave's first tile in half A
    int tB = 36 + wave * 9;   // ... in half B

    const float* gp[2];
    #pragma unroll
    for (int m = 0; m < 2; ++m)
        gp[m] = g + (size_t)(b * NU + u0 + m * 16 + col16) * NH + kgrp * 8;

    f32x4 c[JT][2];
    #pragma unroll
    for (int j = 0; j < JT; ++j) {
        int tile = (j < 9) ? (tA + j) : (tB + j - 9);
        float bv = biasp[tile * 16 + col16];
        f32x4 cv = {bv, bv, bv, bv};
        c[j][0] = cv; c[j][1] = cv;
    }

    // prologue: stage both halves of k-slab 0
    #pragma unroll
    for (int jj = 0; jj < 9; ++jj)
        gload_lds16(WbT + (size_t)(tA + jj) * 512 + lane * 8, &Ws[(tA + jj) * 512]);
    #pragma unroll
    for (int jj = 0; jj < 9; ++jj)
        gload_lds16(WbT + (size_t)(tB + jj) * 512 + lane * 8, &Ws[(tB + jj) * 512]);

    // g prefetch for k-step 0
    f32x4 gpre[2][2];
    #pragma unroll
    for (int m = 0; m < 2; ++m) {
        gpre[m][0] = *(const f32x4*)(gp[m]);
        gpre[m][1] = *(const f32x4*)(gp[m] + 4);
    }

    // consumer-side swizzled slot (lane-invariant)
    int slx = ((kgrp ^ ((col16 >> 2) ^ col16)) & 3) * 8;
    int rdbase = col16 * 32 + slx;

    __syncthreads();   // fs + slab0 staged (barrier drains vmcnt/lgkmcnt)

    for (int ks = 0; ks < KSTEPS; ++ks) {
        int kb = ks * 32 + kgrp * 8;
        f32x4 fa0 = *(const f32x4*)(fs + kb);
        f32x4 fa1 = *(const f32x4*)(fs + kb + 4);
        short8 a0 = pack_relu(fa0 + gpre[0][0], fa1 + gpre[0][1]);
        short8 a1 = pack_relu(fa0 + gpre[1][0], fa1 + gpre[1][1]);
        if (ks < KSTEPS - 1) {
            gpre[0][0] = *(const f32x4*)(gp[0] + (ks + 1) * 32);
            gpre[0][1] = *(const f32x4*)(gp[0] + (ks + 1) * 32 + 4);
            gpre[1][0] = *(const f32x4*)(gp[1] + (ks + 1) * 32);
            gpre[1][1] = *(const f32x4*)(gp[1] + (ks + 1) * 32 + 4);
        }
        // ---- phase A: compute tiles 0-35 @ks (half-B of ks staged in flight) ----
        __builtin_amdgcn_s_setprio(1);
        #pragma unroll
        for (int jj = 0; jj < 9; ++jj) {
            short8 bj = *(const short8*)&Ws[(tA + jj) * 512 + rdbase];
            c[jj][0] = __builtin_amdgcn_mfma_f32_16x16x32_bf16(a0, bj, c[jj][0], 0, 0, 0);
            c[jj][1] = __builtin_amdgcn_mfma_f32_16x16x32_bf16(a1, bj, c[jj][1], 0, 0, 0);
        }
        __builtin_amdgcn_s_setprio(0);
        __syncthreads();   // A-reads done; drains half-B staging of ks
        if (ks < KSTEPS - 1) {
            const unsigned short* wn = WbT + (size_t)(ks + 1) * WSLAB;
            #pragma unroll
            for (int jj = 0; jj < 9; ++jj)
                gload_lds16(wn + (size_t)(tA + jj) * 512 + lane * 8, &Ws[(tA + jj) * 512]);
        }
        // ---- phase B: compute tiles 36-71 @ks (half-A of ks+1 staging overlaps) ----
        __builtin_amdgcn_s_setprio(1);
        #pragma unroll
        for (int jj = 0; jj < 9; ++jj) {
            short8 bj = *(const short8*)&Ws[(tB + jj) * 512 + rdbase];
            c[9 + jj][0] = __builtin_amdgcn_mfma_f32_16x16x32_bf16(a0, bj, c[9 + jj][0], 0, 0, 0);
            c[9 + jj][1] = __builtin_amdgcn_mfma_f32_16x16x32_bf16(a1, bj, c[9 + jj][1], 0, 0, 0);
        }
        __builtin_amdgcn_s_setprio(0);
        __syncthreads();   // B-reads done; drains half-A staging of ks+1
        if (ks < KSTEPS - 1) {
            const unsigned short* wn = WbT + (size_t)(ks + 1) * WSLAB;
            #pragma unroll
            for (int jj = 0; jj < 9; ++jj)
                gload_lds16(wn + (size_t)(tB + jj) * 512 + lane * 8, &Ws[(tB + jj) * 512]);
        }
    }

    // ---- fused log-softmax epilogue ----
    // C layout: col = tile*16 + (lane&15); row = m*16 + (lane>>4)*4 + reg
    float mx[2][4], sl[2][4];
    #pragma unroll
    for (int m = 0; m < 2; ++m) {
        #pragma unroll
        for (int i = 0; i < 4; ++i) {
            float v = -3e38f;
            #pragma unroll
            for (int j = 0; j < JT; ++j) v = fmaxf(v, c[j][m][i]);
            #pragma unroll
            for (int d = 1; d < 16; d <<= 1)
                v = fmaxf(v, __shfl_xor(v, d, 64));
            mx[m][i] = v;
        }
    }
    if (col16 == 0) {
        #pragma unroll
        for (int m = 0; m < 2; ++m)
            #pragma unroll
            for (int i = 0; i < 4; ++i)
                redm[wave][m * 16 + kgrp * 4 + i] = mx[m][i];
    }
    __syncthreads();
    #pragma unroll
    for (int m = 0; m < 2; ++m)
        #pragma unroll
        for (int i = 0; i < 4; ++i) {
            int r = m * 16 + kgrp * 4 + i;
            mx[m][i] = fmaxf(fmaxf(redm[0][r], redm[1][r]), fmaxf(redm[2][r], redm[3][r]));
        }
    #pragma unroll
    for (int m = 0; m < 2; ++m) {
        #pragma unroll
        for (int i = 0; i < 4; ++i) {
            float ssum = 0.f;
            #pragma unroll
            for (int j = 0; j < JT; ++j) ssum += __expf(c[j][m][i] - mx[m][i]);
            #pragma unroll
            for (int d = 1; d < 16; d <<= 1)
                ssum += __shfl_xor(ssum, d, 64);
            sl[m][i] = ssum;
        }
    }
    if (col16 == 0) {
        #pragma unroll
        for (int m = 0; m < 2; ++m)
            #pragma unroll
            for (int i = 0; i < 4; ++i)
                reds[wave][m * 16 + kgrp * 4 + i] = sl[m][i];
    }
    __syncthreads();
    #pragma unroll
    for (int m = 0; m < 2; ++m)
        #pragma unroll
        for (int i = 0; i < 4; ++i) {
            int r = m * 16 + kgrp * 4 + i;
            float S = (reds[0][r] + reds[1][r]) + (reds[2][r] + reds[3][r]);
            sl[m][i] = mx[m][i] + __logf(S);   // m + log(sum exp(x-m))
        }

    size_t orow0 = (size_t)bt * NU + u0;
    #pragma unroll
    for (int m = 0; m < 2; ++m) {
        #pragma unroll
        for (int j = 0; j < JT; ++j) {
            int tile = (j < 9) ? (tA + j) : (tB + j - 9);
            int col = tile * 16 + col16;
            if (col < NV) {
                #pragma unroll
                for (int i = 0; i < 4; ++i) {
                    size_t row = orow0 + m * 16 + kgrp * 4 + i;
                    out[row * (size_t)NV + col] = c[j][m][i] - sl[m][i];
                }
            }
        }
    }
}

extern "C" void kernel_launch(void* const* d_in, const int* in_sizes, int n_in,
                              void* d_out, int out_size, void* d_ws, size_t ws_size,
                              hipStream_t stream) {
    const float* enc    = (const float*)d_in[0];  // [4][512][256]
    const float* dec    = (const float*)d_in[1];  // [4][640][128]
    const float* W_enc  = (const float*)d_in[2];  // [640][512]
    const float* b_enc  = (const float*)d_in[3];  // [640]
    const float* W_pred = (const float*)d_in[4];  // [640][640]
    const float* b_pred = (const float*)d_in[5];  // [640]
    const float* W_out  = (const float*)d_in[6];  // [1025][640]
    const float* b_out  = (const float*)d_in[7];  // [1025]
    float* out = (float*)d_out;

    char* ws = (char*)d_ws;
    unsigned short* WbT = (unsigned short*)ws;         // 1,474,560 B (bf16 [20][1152][32])
    float* biasp = (float*)(ws + 1474560);             // 4,608 B
    float* fbuf  = (float*)(ws + 1479168);             // 2,621,440 B ([1024][640] fp32)
    float* gbuf  = (float*)(ws + 4100608);             // 1,310,720 B ([512][640] fp32)

    prep_kernel<<<dim3(WSLAB / 256, KSTEPS), 256, 0, stream>>>(W_out, b_out, WbT, biasp);
    proj_kernel<<<dim3((NB * NT) / 32, NH / 64), 256, 0, stream>>>(enc, W_enc, b_enc, fbuf, NT, DENC);
    proj_kernel<<<dim3((NB * NU) / 32, NH / 64), 256, 0, stream>>>(dec, W_pred, b_pred, gbuf, NU, DPRED);
    joint_kernel<<<NB * NT * (NU / 32), 256, 0, stream>>>(fbuf, gbuf, WbT, biasp, out);
}

// Round 5
// 903.035 us; speedup vs baseline: 1.3830x; 1.1107x over previous
//
#include <hip/hip_runtime.h>
#include <hip/hip_bf16.h>

// Problem constants
#define NB 4
#define NT 256
#define NU 128
#define DENC 512
#define DPRED 640
#define NH 640
#define NV 1025
#define NVP 1088      // V padded to 68 tiles of 16 -> 17 tiles per wave (4 waves)
#define NTILES 68
#define JTA 8         // phase-A tiles per wave
#define JTB 9         // phase-B tiles per wave
#define JT 17         // JTA + JTB
#define KSTEPS 20     // 640 / 32
#define WSLAB (NVP * 32)   // 34816 bf16 elems per k-slab (69632 B)

typedef __attribute__((ext_vector_type(8))) short short8;
typedef __attribute__((ext_vector_type(4))) float f32x4;

__device__ __forceinline__ unsigned short bfu(float a) {
    union { __hip_bfloat16 h; unsigned short u; } cv;
    cv.h = __float2bfloat16(a);
    return cv.u;
}

__device__ __forceinline__ unsigned pk2(float a, float b) {
    union { __hip_bfloat162 h; unsigned u; } cv;
    cv.h = __float22bfloat162_rn(float2{a, b});
    return cv.u;
}

__device__ __forceinline__ short8 pack_relu(f32x4 x, f32x4 y) {
    union { short8 s; unsigned u[4]; } r;
    r.u[0] = pk2(fmaxf(x[0], 0.f), fmaxf(x[1], 0.f));
    r.u[1] = pk2(fmaxf(x[2], 0.f), fmaxf(x[3], 0.f));
    r.u[2] = pk2(fmaxf(y[0], 0.f), fmaxf(y[1], 0.f));
    r.u[3] = pk2(fmaxf(y[2], 0.f), fmaxf(y[3], 0.f));
    return r.s;
}

// async global -> LDS, 16 B per lane; LDS dest = wave-uniform base + lane*16
__device__ __forceinline__ void gload_lds16(const void* g, void* l) {
    __builtin_amdgcn_global_load_lds(
        (const __attribute__((address_space(1))) unsigned int*)g,
        (__attribute__((address_space(3))) unsigned int*)l, 16, 0, 0);
}

// prep: W_out fp32 [1025][640] -> WbT bf16 [21][1088][32] (k-slab-major; slab 20
// is a zero dummy so the joint loop can prefetch branch-free on its last iter).
// LDS bank-swizzle pre-baked: (r, slot s) holds source slot s ^ f(r),
// f(r) = ((r>>2)^r)&3. Consumer reads slot kgrp^f(row) -> original data.
// bias -> [1088], pads = -1e30. Grid: dim3(136, 21).
__global__ __launch_bounds__(256) void prep_kernel(const float* __restrict__ Wo,
                                                   const float* __restrict__ bo,
                                                   unsigned short* __restrict__ WbT,
                                                   float* __restrict__ biasp) {
    int idx = blockIdx.x * 256 + threadIdx.x;     // 0 .. 34815 within slab
    int ks = blockIdx.y;                          // 0 .. 20
    int r = idx >> 5;         // row 0..1087
    int kk = idx & 31;        // 0..31 within slab row
    int s = kk >> 3, e = kk & 7;
    int f = ((r >> 2) ^ r) & 3;
    int scol = ks * 32 + (((s ^ f) & 3) << 3) + e;
    unsigned short val = 0;
    if (ks < KSTEPS && r < NV) val = bfu(Wo[r * NH + scol]);
    WbT[(size_t)ks * WSLAB + idx] = val;
    if (ks == 0 && idx < NVP) biasp[idx] = (idx < NV) ? bo[idx] : -1e30f;
}

// Projection GEMM: out[b*L + l][n] = sum_k X[b][k][l] * W[n][k] + bias[n]
__global__ __launch_bounds__(256) void proj_kernel(const float* __restrict__ X,
                                                   const float* __restrict__ W,
                                                   const float* __restrict__ bias,
                                                   float* __restrict__ out,
                                                   int L, int K) {
    __shared__ unsigned short As[32][40];
    __shared__ unsigned short Bs[64][40];
    int tid = threadIdx.x;
    int wave = tid >> 6, lane = tid & 63;
    int col16 = lane & 15, kgrp = lane >> 4;
    int m0 = blockIdx.x * 32;
    int n0 = blockIdx.y * 64;
    int b = m0 / L, l0 = m0 % L;
    const float* Xb = X + (size_t)b * K * L;

    float bv = bias[n0 + wave * 16 + col16];
    f32x4 c0 = {bv, bv, bv, bv};
    f32x4 c1 = c0;

    int ac = tid >> 3;
    int ar = (tid & 7) * 4;
    int bn = tid >> 2;
    int bc = (tid & 3) * 8;

    for (int k0 = 0; k0 < K; k0 += 32) {
        f32x4 av  = *(const f32x4*)(Xb + (size_t)(k0 + ac) * L + l0 + ar);
        f32x4 bw0 = *(const f32x4*)(W + (size_t)(n0 + bn) * K + k0 + bc);
        f32x4 bw1 = *(const f32x4*)(W + (size_t)(n0 + bn) * K + k0 + bc + 4);
        __syncthreads();
        As[ar + 0][ac] = bfu(av[0]);
        As[ar + 1][ac] = bfu(av[1]);
        As[ar + 2][ac] = bfu(av[2]);
        As[ar + 3][ac] = bfu(av[3]);
        unsigned* bsrow = (unsigned*)&Bs[bn][bc];
        bsrow[0] = pk2(bw0[0], bw0[1]);
        bsrow[1] = pk2(bw0[2], bw0[3]);
        bsrow[2] = pk2(bw1[0], bw1[1]);
        bsrow[3] = pk2(bw1[2], bw1[3]);
        __syncthreads();
        short8 a0  = *(const short8*)&As[col16][kgrp * 8];
        short8 a1  = *(const short8*)&As[16 + col16][kgrp * 8];
        short8 bfr = *(const short8*)&Bs[wave * 16 + col16][kgrp * 8];
        c0 = __builtin_amdgcn_mfma_f32_16x16x32_bf16(a0, bfr, c0, 0, 0, 0);
        c1 = __builtin_amdgcn_mfma_f32_16x16x32_bf16(a1, bfr, c1, 0, 0, 0);
    }
    int n = n0 + wave * 16 + col16;
    #pragma unroll
    for (int i = 0; i < 4; ++i) {
        int r0 = kgrp * 4 + i;
        out[(size_t)(m0 + r0) * NH + n]      = c0[i];
        out[(size_t)(m0 + 16 + r0) * NH + n] = c1[i];
    }
}

// Joint kernel v6: M=32, 256 thr, 4 waves x 17 tiles. NO main-loop barriers:
// each wave stages and consumes ONLY its own tiles, self-synced with counted
// vmcnt waits (queue invariant [g4, A8, B9] = 21 in flight; wait vmcnt(13)
// before phase A, vmcnt(12) before phase B -- never drain to 0). Slab 20 is a
// zero dummy so the last iteration prefetches branch-free.
__global__ __launch_bounds__(256, 2) void joint_kernel(const float* __restrict__ f,
                                                       const float* __restrict__ g,
                                                       const unsigned short* __restrict__ WbT,
                                                       const float* __restrict__ biasp,
                                                       float* __restrict__ out) {
    __shared__ unsigned short Ws[WSLAB];   // 69632 B, tile t at elem t*512
    __shared__ float fs[NH];
    __shared__ float redm[4][32];
    __shared__ float reds[4][32];
    int tid = threadIdx.x;
    int wave = tid >> 6, lane = tid & 63;
    int col16 = lane & 15, kgrp = lane >> 4;
    int bt = blockIdx.x >> 2;          // b*NT + t
    int u0 = (blockIdx.x & 3) * 32;
    int b = bt >> 8;                   // NT = 256

    for (int i = tid; i < NH; i += 256) fs[i] = f[(size_t)bt * NH + i];

    int tstart = wave * JT;            // 0,17,34,51
    unsigned short* WsA = &Ws[tstart * 512];
    unsigned short* WsB = &Ws[(tstart + JTA) * 512];

    const float* gp0 = g + (size_t)(b * NU + u0 + col16) * NH + kgrp * 8;
    const float* gp1 = gp0 + 16 * NH;

    f32x4 c[JT][2];
    #pragma unroll
    for (int j = 0; j < JT; ++j) {
        float bv = biasp[(tstart + j) * 16 + col16];
        f32x4 cv = {bv, bv, bv, bv};
        c[j][0] = cv; c[j][1] = cv;
    }

    // consumer-side swizzled slot (lane-invariant)
    int slx = ((kgrp ^ ((col16 >> 2) ^ col16)) & 3) * 8;
    int rdbase = col16 * 32 + slx;

    __syncthreads();   // fs visible to all waves (drains everything; count=0)

    // ---- prologue: establish queue [g0(4), A0(8), B0(9)] = 21 in flight ----
    f32x4 ga0 = *(const f32x4*)(gp0);
    f32x4 ga1 = *(const f32x4*)(gp0 + 4);
    f32x4 gb0 = *(const f32x4*)(gp1);
    f32x4 gb1 = *(const f32x4*)(gp1 + 4);
    #pragma unroll
    for (int jj = 0; jj < JTA; ++jj)
        gload_lds16(WbT + (size_t)(tstart + jj) * 512 + lane * 8, WsA + jj * 512);
    #pragma unroll
    for (int jj = 0; jj < JTB; ++jj)
        gload_lds16(WbT + (size_t)(tstart + JTA + jj) * 512 + lane * 8, WsB + jj * 512);

    for (int ks = 0; ks < KSTEPS; ++ks) {
        int kb = ks * 32 + kgrp * 8;
        f32x4 fa0 = *(const f32x4*)(fs + kb);
        f32x4 fa1 = *(const f32x4*)(fs + kb + 4);
        // compiler inserts counted vmcnt for g_ks here (oldest 4 in queue)
        short8 a0 = pack_relu(fa0 + ga0, fa1 + ga1);
        short8 a1 = pack_relu(fa0 + gb0, fa1 + gb1);
        // issue g_{ks+1} (ks=19 reads 8 elems past row end -- in-bounds garbage)
        ga0 = *(const f32x4*)(gp0 + (ks + 1) * 32);
        ga1 = *(const f32x4*)(gp0 + (ks + 1) * 32 + 4);
        gb0 = *(const f32x4*)(gp1 + (ks + 1) * 32);
        gb1 = *(const f32x4*)(gp1 + (ks + 1) * 32 + 4);
        // wait A_ks landed: leave B_ks(9) + g_next(4) = 13 in flight
        asm volatile("s_waitcnt vmcnt(13)" ::: "memory");
        __builtin_amdgcn_sched_barrier(0);
        __builtin_amdgcn_s_setprio(1);
        #pragma unroll
        for (int jj = 0; jj < JTA; ++jj) {
            short8 bj = *(const short8*)(WsA + jj * 512 + rdbase);
            c[jj][0] = __builtin_amdgcn_mfma_f32_16x16x32_bf16(a0, bj, c[jj][0], 0, 0, 0);
            c[jj][1] = __builtin_amdgcn_mfma_f32_16x16x32_bf16(a1, bj, c[jj][1], 0, 0, 0);
        }
        __builtin_amdgcn_s_setprio(0);
        // A-half ds_reads complete before the DMA below can overwrite it
        asm volatile("s_waitcnt lgkmcnt(0)" ::: "memory");
        __builtin_amdgcn_sched_barrier(0);
        const unsigned short* wn = WbT + (size_t)(ks + 1) * WSLAB;   // slab 20 = zeros
        #pragma unroll
        for (int jj = 0; jj < JTA; ++jj)
            gload_lds16(wn + (size_t)(tstart + jj) * 512 + lane * 8, WsA + jj * 512);
        // wait B_ks landed: leave g_next(4) + A_next(8) = 12 in flight
        asm volatile("s_waitcnt vmcnt(12)" ::: "memory");
        __builtin_amdgcn_sched_barrier(0);
        __builtin_amdgcn_s_setprio(1);
        #pragma unroll
        for (int jj = 0; jj < JTB; ++jj) {
            short8 bj = *(const short8*)(WsB + jj * 512 + rdbase);
            c[JTA + jj][0] = __builtin_amdgcn_mfma_f32_16x16x32_bf16(a0, bj, c[JTA + jj][0], 0, 0, 0);
            c[JTA + jj][1] = __builtin_amdgcn_mfma_f32_16x16x32_bf16(a1, bj, c[JTA + jj][1], 0, 0, 0);
        }
        __builtin_amdgcn_s_setprio(0);
        asm volatile("s_waitcnt lgkmcnt(0)" ::: "memory");
        __builtin_amdgcn_sched_barrier(0);
        #pragma unroll
        for (int jj = 0; jj < JTB; ++jj)
            gload_lds16(wn + (size_t)(tstart + JTA + jj) * 512 + lane * 8, WsB + jj * 512);
    }

    __syncthreads();   // drains the dummy prefetches; sync for reductions

    // ---- fused log-softmax epilogue ----
    // C layout: col = tile*16 + (lane&15); row = m*16 + (lane>>4)*4 + reg
    float mx[2][4], sl[2][4];
    #pragma unroll
    for (int m = 0; m < 2; ++m) {
        #pragma unroll
        for (int i = 0; i < 4; ++i) {
            float v = -3e38f;
            #pragma unroll
            for (int j = 0; j < JT; ++j) v = fmaxf(v, c[j][m][i]);
            #pragma unroll
            for (int d = 1; d < 16; d <<= 1)
                v = fmaxf(v, __shfl_xor(v, d, 64));
            mx[m][i] = v;
        }
    }
    if (col16 == 0) {
        #pragma unroll
        for (int m = 0; m < 2; ++m)
            #pragma unroll
            for (int i = 0; i < 4; ++i)
                redm[wave][m * 16 + kgrp * 4 + i] = mx[m][i];
    }
    __syncthreads();
    #pragma unroll
    for (int m = 0; m < 2; ++m)
        #pragma unroll
        for (int i = 0; i < 4; ++i) {
            int r = m * 16 + kgrp * 4 + i;
            mx[m][i] = fmaxf(fmaxf(redm[0][r], redm[1][r]), fmaxf(redm[2][r], redm[3][r]));
        }
    #pragma unroll
    for (int m = 0; m < 2; ++m) {
        #pragma unroll
        for (int i = 0; i < 4; ++i) {
            float ssum = 0.f;
            #pragma unroll
            for (int j = 0; j < JT; ++j) ssum += __expf(c[j][m][i] - mx[m][i]);
            #pragma unroll
            for (int d = 1; d < 16; d <<= 1)
                ssum += __shfl_xor(ssum, d, 64);
            sl[m][i] = ssum;
        }
    }
    if (col16 == 0) {
        #pragma unroll
        for (int m = 0; m < 2; ++m)
            #pragma unroll
            for (int i = 0; i < 4; ++i)
                reds[wave][m * 16 + kgrp * 4 + i] = sl[m][i];
    }
    __syncthreads();
    #pragma unroll
    for (int m = 0; m < 2; ++m)
        #pragma unroll
        for (int i = 0; i < 4; ++i) {
            int r = m * 16 + kgrp * 4 + i;
            float S = (reds[0][r] + reds[1][r]) + (reds[2][r] + reds[3][r]);
            sl[m][i] = mx[m][i] + __logf(S);   // m + log(sum exp(x-m))
        }

    size_t orow0 = (size_t)bt * NU + u0;
    #pragma unroll
    for (int m = 0; m < 2; ++m) {
        #pragma unroll
        for (int j = 0; j < JT; ++j) {
            int col = (tstart + j) * 16 + col16;
            if (col < NV) {
                #pragma unroll
                for (int i = 0; i < 4; ++i) {
                    size_t row = orow0 + m * 16 + kgrp * 4 + i;
                    out[row * (size_t)NV + col] = c[j][m][i] - sl[m][i];
                }
            }
        }
    }
}

extern "C" void kernel_launch(void* const* d_in, const int* in_sizes, int n_in,
                              void* d_out, int out_size, void* d_ws, size_t ws_size,
                              hipStream_t stream) {
    const float* enc    = (const float*)d_in[0];  // [4][512][256]
    const float* dec    = (const float*)d_in[1];  // [4][640][128]
    const float* W_enc  = (const float*)d_in[2];  // [640][512]
    const float* b_enc  = (const float*)d_in[3];  // [640]
    const float* W_pred = (const float*)d_in[4];  // [640][640]
    const float* b_pred = (const float*)d_in[5];  // [640]
    const float* W_out  = (const float*)d_in[6];  // [1025][640]
    const float* b_out  = (const float*)d_in[7];  // [1025]
    float* out = (float*)d_out;

    char* ws = (char*)d_ws;
    unsigned short* WbT = (unsigned short*)ws;         // 1,462,272 B (bf16 [21][1088][32])
    float* biasp = (float*)(ws + 1462272);             // 4,352 B
    float* fbuf  = (float*)(ws + 1466624);             // 2,621,440 B ([1024][640] fp32)
    float* gbuf  = (float*)(ws + 4088064);             // 1,310,720 B ([512][640] fp32)

    prep_kernel<<<dim3(WSLAB / 256, KSTEPS + 1), 256, 0, stream>>>(W_out, b_out, WbT, biasp);
    proj_kernel<<<dim3((NB * NT) / 32, NH / 64), 256, 0, stream>>>(enc, W_enc, b_enc, fbuf, NT, DENC);
    proj_kernel<<<dim3((NB * NU) / 32, NH / 64), 256, 0, stream>>>(dec, W_pred, b_pred, gbuf, NU, DPRED);
    joint_kernel<<<NB * NT * (NU / 32), 256, 0, stream>>>(fbuf, gbuf, WbT, biasp, out);
}